// Round 8
// baseline (34.594 us; speedup 1.0000x reference)
//
#include <hip/hip_runtime.h>

#define BB 32
#define NN 1024
#define DD 256

// Two plain launches, split exactly at the data dependency (no inter-block
// sync of any kind — rounds 1-7 showed every sync flavor stalls or poisons
// caches). Decisive A/B vs the spin-based fused kernel:
//   K1: fused-style phase 1 — float4/lane streaming (1 KB per wave-instr,
//       vs 256 B in the round-0 baseline K1), in-register col-sums, LDS
//       cross-wave reduce, ONE relaxed device-scope atomicAdd per thread
//       into the final fsum[64][256] (64 KB). No partial buffer round-trip.
//   K2: reads fsum (1 float/thread) + re-reads rows from L3 (64 MB input
//       fits the 256 MB LLC that K1 just streamed through), dot + shfl.
#define NSLICE 64                 // 2 tensors * 32 batches
#define BPS 16                    // blocks per slice
#define NBLOCKS (NSLICE * BPS)    // 1024
#define RPB 64                    // rows per block
#define RPW 16                    // rows per wave (4 waves/block)

#define WS_FSUM_BYTES (NSLICE * DD * 4)   // 64 KB, memset 0 each launch

__global__ __launch_bounds__(256)
void sum_kernel(const float* __restrict__ x, const float* __restrict__ y,
                float* __restrict__ fsum) {           // [NSLICE][DD]
    const int bid   = blockIdx.x;
    const int slice = bid / BPS;        // 0..31 = x batches, 32..63 = y batches
    const int chunk = bid % BPS;
    const int t     = slice >> 5;
    const int b     = slice & 31;
    const int lane  = threadIdx.x & 63;
    const int wave  = threadIdx.x >> 6;
    const int d     = threadIdx.x;

    const int row0 = chunk * RPB + wave * RPW;
    const float4* srcv = reinterpret_cast<const float4*>(
        (t == 0 ? x : y) + (size_t)b * NN * DD) + (size_t)row0 * (DD / 4) + lane;

    // 16 rows per wave, float4 per lane: each wave-instr reads 1 KB contiguous.
    float4 p = make_float4(0.f, 0.f, 0.f, 0.f);
    #pragma unroll
    for (int r = 0; r < RPW; ++r) {
        float4 v = srcv[(size_t)r * (DD / 4)];
        p.x += v.x; p.y += v.y; p.z += v.z; p.w += v.w;
    }

    __shared__ float lds[4][DD];
    *reinterpret_cast<float4*>(&lds[wave][lane * 4]) = p;
    __syncthreads();
    float ps = lds[0][d] + lds[1][d] + lds[2][d] + lds[3][d];

    // Final-sum accumulation: one relaxed device-scope fp32 add per thread.
    __hip_atomic_fetch_add(&fsum[(size_t)slice * DD + d], ps,
                           __ATOMIC_RELAXED, __HIP_MEMORY_SCOPE_AGENT);
}

__global__ __launch_bounds__(256)
void dots2_kernel(const float* __restrict__ x, const float* __restrict__ y,
                  const float* __restrict__ fsum,     // [NSLICE][DD]
                  float* __restrict__ out) {
    const int bid   = blockIdx.x;
    const int slice = bid / BPS;
    const int chunk = bid % BPS;
    const int t     = slice >> 5;       // 0: dot x-rows with ysum (colsum out)
    const int b     = slice & 31;
    const int lane  = threadIdx.x & 63;
    const int wave  = threadIdx.x >> 6;
    const int d     = threadIdx.x;
    const int opp   = slice ^ 32;       // opposite tensor, same batch

    __shared__ float ssum[DD];
    ssum[d] = fsum[(size_t)opp * DD + d];
    __syncthreads();

    const float4 sv = *reinterpret_cast<const float4*>(&ssum[lane * 4]);

    const float* data = (t == 0 ? x : y) + (size_t)b * NN * DD;
    // t==0 (x rows · ysum): colsum -> out[b][1024+n]
    // t==1 (y rows · xsum): rowsum -> out[b][m]
    float* outp = out + (size_t)b * 2048 + (t == 0 ? 1024 : 0);

    const int row0 = chunk * RPB + wave * RPW;
    #pragma unroll 4
    for (int r = 0; r < RPW; ++r) {
        const int row = row0 + r;
        float4 v = *reinterpret_cast<const float4*>(&data[(size_t)row * DD + lane * 4]);
        float dv = v.x * sv.x + v.y * sv.y + v.z * sv.z + v.w * sv.w;
        #pragma unroll
        for (int off = 32; off >= 1; off >>= 1)
            dv += __shfl_down(dv, off, 64);
        if (lane == 0) outp[row] = dv;
    }
}

extern "C" void kernel_launch(void* const* d_in, const int* in_sizes, int n_in,
                              void* d_out, int out_size, void* d_ws, size_t ws_size,
                              hipStream_t stream) {
    const float* x = (const float*)d_in[0];
    const float* y = (const float*)d_in[1];
    float* out     = (float*)d_out;
    float* fsum    = (float*)d_ws;

    hipMemsetAsync(fsum, 0, WS_FSUM_BYTES, stream);
    sum_kernel<<<NBLOCKS, 256, 0, stream>>>(x, y, fsum);
    dots2_kernel<<<NBLOCKS, 256, 0, stream>>>(x, y, fsum, out);
}